// Round 2
// baseline (100.585 us; speedup 1.0000x reference)
//
#include <hip/hip_runtime.h>
#include <hip/hip_bf16.h>

typedef __bf16 bf8 __attribute__((ext_vector_type(8)));
typedef __bf16 bf4 __attribute__((ext_vector_type(4)));
typedef unsigned short u16x8 __attribute__((ext_vector_type(8)));
typedef unsigned short u16x4 __attribute__((ext_vector_type(4)));
typedef float f32x4 __attribute__((ext_vector_type(4)));
typedef float f32x2 __attribute__((ext_vector_type(2)));

union FragU { u16x8 u; bf8 b; };
union Pk4 { u16x4 u; bf4 b; };

struct __attribute__((packed, aligned(4))) F4u { float v[4]; };
struct __attribute__((packed, aligned(4))) F2u { float v[2]; };

static __device__ __forceinline__ f32x4 MM(const FragU& a, const FragU& b, f32x4 c) {
  return __builtin_amdgcn_mfma_f32_16x16x32_bf16(a.b, b.b, c, 0, 0, 0);
}

#define NBATCH 524288
#define NTIL (NBATCH / 64)
#define GRID 768

// per-wave scratch (ushort units): hbuf [16][72] = 1152, then 4 regions [16][40] = 2560
#define PWS 3712
#define HB 0
#define RG 1152

__global__ __launch_bounds__(256, 3) void cdann_fwd(
    const float* __restrict__ gx, const int* __restrict__ gy,
    const float* __restrict__ gWf1, const float* __restrict__ gbf1,
    const float* __restrict__ gWf2, const float* __restrict__ gbf2,
    const float* __restrict__ gWt1, const float* __restrict__ gbt1,
    const float* __restrict__ gWt2, const float* __restrict__ gbt2,
    const float* __restrict__ gWp1, const float* __restrict__ gbp1,
    const float* __restrict__ gWp2, const float* __restrict__ gbp2,
    const float* __restrict__ gWp3, const float* __restrict__ gbp3,
    const float* __restrict__ gWc1, const float* __restrict__ gbc1,
    const float* __restrict__ gWc2, const float* __restrict__ gbc2,
    const float* __restrict__ gWc3, const float* __restrict__ gbc3,
    float* __restrict__ gout)
{
  __shared__ __align__(16) unsigned short lds[4 * PWS];
  const int tid = (int)threadIdx.x;
  const int lane = tid & 63;
  const int w = tid >> 6;
  const int g = lane >> 4;
  const int c15 = lane & 15;
  unsigned short* hbuf = lds + w * PWS + HB;   // [16][72]
  unsigned short* reg4 = lds + w * PWS + RG;   // 4 x [16][40]

  // ---- init const-1/zero slots (offsets 20..31 of each region row); never overwritten ----
  {
    unsigned short* rp = reg4 + g * 640 + c15 * 40;
    u16x4 one0 = {0x3F80u, 0u, 0u, 0u};
    u16x4 zz = {0u, 0u, 0u, 0u};
    *(u16x4*)(rp + 20) = one0;
    *(u16x4*)(rp + 24) = zz;
    *(u16x4*)(rp + 28) = zz;
  }

  // ---- build weight fragments: A-operand = W^T, lane: row n=(l&15), k=(l>>4)*8+j ----
  auto mk = [&](int ks, int nt, auto&& src) {
    FragU f;
    const int kb = ks * 32 + g * 8;
    const int n = nt * 16 + c15;
#pragma unroll
    for (int j = 0; j < 8; ++j) f.b[j] = (__bf16)src(kb + j, n);
    return f;
  };
  auto s_f1 = [&](int k, int n) -> float {           // K=32 (30 + const1), N=64
    if (k < 30) return gWf1[k * 64 + n];
    if (k == 30) return gbf1[n];
    return 0.f;
  };
  auto s_f2 = [&](int k, int n) -> float {           // K=64, N=48 (42 valid)
    return (n < 42) ? gWf2[k * 42 + n] : 0.f;
  };
  auto s_quad = [&](int k, int n) -> float {         // packed [t1|p1|c1e0|c1e1], N=80, const1 at k=42
    if (n < 20) { if (k < 42) return gWt1[k * 20 + n]; if (k == 42) return gbt1[n]; return 0.f; }
    if (n < 40) { int m = n - 20; if (k < 42) return gWp1[k * 20 + m]; if (k == 42) return gbp1[m]; return 0.f; }
    if (n < 60) { int m = n - 40; if (k < 42) return gWc1[k * 20 + m]; if (k == 42) return gbc1[m]; return 0.f; }
    int m = n - 60;
    if (k < 42) return gWc1[(42 + k) * 20 + m];
    if (k == 42) return gbc1[20 + m];
    return 0.f;
  };
  auto s_t2 = [&](int k, int n) -> float {
    if (n >= 2) return 0.f;
    if (k < 20) return gWt2[k * 2 + n];
    if (k == 20) return gbt2[n];
    return 0.f;
  };
  auto s_p2 = [&](int k, int n) -> float {
    if (n >= 20) return 0.f;
    if (k < 20) return gWp2[k * 20 + n];
    if (k == 20) return gbp2[n];
    return 0.f;
  };
  auto s_p3 = [&](int k, int n) -> float {
    if (n >= 6) return 0.f;
    if (k < 20) return gWp3[k * 6 + n];
    if (k == 20) return gbp3[n];
    return 0.f;
  };
  auto s_c2 = [&](int e, int k, int n) -> float {
    if (n >= 20) return 0.f;
    if (k < 20) return gWc2[(e * 20 + k) * 20 + n];
    if (k == 20) return gbc2[e * 20 + n];
    return 0.f;
  };
  auto s_c3 = [&](int e, int k, int n) -> float {
    if (n >= 6) return 0.f;
    if (k < 20) return gWc3[(e * 20 + k) * 6 + n];
    if (k == 20) return gbc3[e * 6 + n];
    return 0.f;
  };

  FragU wF1[4], wF2[2][3], wQ[2][5];
  FragU wT2, wP2[2], wP3, wC2a[2], wC2b[2], wC3a, wC3b;
#pragma unroll
  for (int nt = 0; nt < 4; ++nt) wF1[nt] = mk(0, nt, s_f1);
#pragma unroll
  for (int ks = 0; ks < 2; ++ks) {
#pragma unroll
    for (int nt = 0; nt < 3; ++nt) wF2[ks][nt] = mk(ks, nt, s_f2);
#pragma unroll
    for (int nt = 0; nt < 5; ++nt) wQ[ks][nt] = mk(ks, nt, s_quad);
  }
  wT2 = mk(0, 0, s_t2);
#pragma unroll
  for (int nt = 0; nt < 2; ++nt) {
    wP2[nt]  = mk(0, nt, s_p2);
    wC2a[nt] = mk(0, nt, [&](int k, int n){ return s_c2(0, k, n); });
    wC2b[nt] = mk(0, nt, [&](int k, int n){ return s_c2(1, k, n); });
  }
  wP3  = mk(0, 0, s_p3);
  wC3a = mk(0, 0, [&](int k, int n){ return s_c3(0, k, n); });
  wC3b = mk(0, 0, [&](int k, int n){ return s_c3(1, k, n); });

  // f2 bias (K=64 full, can't fold): 12 per-lane regs
  float biasF2[3][4];
#pragma unroll
  for (int nt = 0; nt < 3; ++nt)
#pragma unroll
    for (int r = 0; r < 4; ++r) {
      int n = nt * 16 + g * 4 + r;
      biasF2[nt][r] = (n < 42) ? gbf2[n] : 0.f;
    }

  const f32x4 zf = {0.f, 0.f, 0.f, 0.f};
  float* const outT = gout;
  float* const outP = gout + (size_t)2 * NBATCH;
  float* const outC = gout + (size_t)8 * NBATCH;

  // ---- direct global x load: lane (g,c15) reads x[s][g*8 .. g*8+7] (g=3: 24..29 + const1 + 0) ----
  float xr[8];
  auto loadx = [&](int it) {
    const int s = it * 64 + w * 16 + c15;
    const float* xp = gx + (size_t)s * 30 + g * 8;
    if (g < 3) {
      F4u a = *(const F4u*)xp;
      F4u b = *(const F4u*)(xp + 4);
#pragma unroll
      for (int j = 0; j < 4; ++j) { xr[j] = a.v[j]; xr[4 + j] = b.v[j]; }
    } else {
      F4u a = *(const F4u*)xp;
      F2u b = *(const F2u*)(xp + 4);
#pragma unroll
      for (int j = 0; j < 4; ++j) xr[j] = a.v[j];
      xr[4] = b.v[0]; xr[5] = b.v[1];
      xr[6] = 1.0f; xr[7] = 0.0f;   // k=30 const1 (bias fold), k=31 zero
    }
  };

  int it = (int)blockIdx.x;
  loadx(it);

  while (it < NTIL) {
    const int nit = it + GRID;
    const int sg = it * 64 + w * 16 + c15;
    const int ys = gy[sg];

    // convert prefetched x -> B frag
    FragU bx;
#pragma unroll
    for (int j = 0; j < 8; ++j) bx.b[j] = (__bf16)xr[j];

    // issue next tile's loads now; they complete under the chain
    if (nit < NTIL) loadx(nit);

    // ---- f1: x(K=32) -> h(N=64), bias folded ----
    f32x4 aH[4];
#pragma unroll
    for (int nt = 0; nt < 4; ++nt) aH[nt] = MM(wF1[nt], bx, zf);
#pragma unroll
    for (int nt = 0; nt < 4; ++nt) {
      Pk4 hv;
#pragma unroll
      for (int r = 0; r < 4; ++r) hv.b[r] = (__bf16)fmaxf(aH[nt][r], 0.f);
      *(u16x4*)(hbuf + c15 * 72 + nt * 16 + g * 4) = hv.u;
    }

    // ---- f2: h(K=64) -> fea(N=48; 42 valid, const1 at 42, zeros 43..63) ----
    FragU bh0, bh1;
    bh0.u = *(const u16x8*)(hbuf + c15 * 72 + g * 8);
    bh1.u = *(const u16x8*)(hbuf + c15 * 72 + 32 + g * 8);
#pragma unroll
    for (int nt = 0; nt < 3; ++nt) {
      f32x4 a = MM(wF2[1][nt], bh1, MM(wF2[0][nt], bh0, zf));
      float v[4];
#pragma unroll
      for (int r = 0; r < 4; ++r) v[r] = fmaxf(a[r] + biasF2[nt][r], 0.f);
      if (nt == 2) {
        if (g == 2) { v[2] = 1.0f; v[3] = 0.f; }   // fea[42]=const1, fea[43]=0
        if (g == 3) { v[0] = 0.f; v[1] = 0.f; v[2] = 0.f; v[3] = 0.f; }
      }
      Pk4 fv;
#pragma unroll
      for (int r = 0; r < 4; ++r) fv.b[r] = (__bf16)v[r];
      *(u16x4*)(hbuf + c15 * 72 + nt * 16 + g * 4) = fv.u;
    }
    {
      u16x4 zz = {0u, 0u, 0u, 0u};                 // zero fea[48..63]
      *(u16x4*)(hbuf + c15 * 72 + 48 + g * 4) = zz;
    }

    // ---- quad: fea(K=64) -> [t1|p1|c1e0|c1e1] (N=80) ----
    FragU be0, be1;
    be0.u = *(const u16x8*)(hbuf + c15 * 72 + g * 8);
    be1.u = *(const u16x8*)(hbuf + c15 * 72 + 32 + g * 8);
#pragma unroll
    for (int nt = 0; nt < 5; ++nt) {
      f32x4 a = MM(wQ[1][nt], be1, MM(wQ[0][nt], be0, zf));
      Pk4 vv;
#pragma unroll
      for (int r = 0; r < 4; ++r) vv.b[r] = (__bf16)fmaxf(a[r], 0.f);
      const int q = nt * 16 + g * 4;               // 0..76, step 4; region = q/20
      const int reg = q / 20;
      const int off = q - reg * 20;
      *(u16x4*)(reg4 + reg * 640 + c15 * 40 + off) = vv.u;
    }

    // ---- t2: t(K=32) -> task (n=0,1) ----
    FragU bt; bt.u = *(const u16x8*)(reg4 + c15 * 40 + g * 8);
    f32x4 at = MM(wT2, bt, zf);

    // ---- p2: p1(K=32) -> p2(20), write into R0 (t dead) ----
    FragU bp1f; bp1f.u = *(const u16x8*)(reg4 + 640 + c15 * 40 + g * 8);
#pragma unroll
    for (int nt = 0; nt < 2; ++nt) {
      f32x4 a = MM(wP2[nt], bp1f, zf);
      const int q = nt * 16 + g * 4;
      if (q < 20) {
        Pk4 vv;
#pragma unroll
        for (int r = 0; r < 4; ++r) vv.b[r] = (__bf16)fmaxf(a[r], 0.f);
        *(u16x4*)(reg4 + c15 * 40 + q) = vv.u;
      }
    }
    // ---- p3: p2(K=32) -> pd (n=0..5) ----
    FragU bp2f; bp2f.u = *(const u16x8*)(reg4 + c15 * 40 + g * 8);
    f32x4 ap = MM(wP3, bp2f, zf);

    // ---- c2e0: c1e0(K=32) -> c2e0(20), write into R1 (p1 dead) ----
    FragU bc0; bc0.u = *(const u16x8*)(reg4 + 1280 + c15 * 40 + g * 8);
#pragma unroll
    for (int nt = 0; nt < 2; ++nt) {
      f32x4 a = MM(wC2a[nt], bc0, zf);
      const int q = nt * 16 + g * 4;
      if (q < 20) {
        Pk4 vv;
#pragma unroll
        for (int r = 0; r < 4; ++r) vv.b[r] = (__bf16)fmaxf(a[r], 0.f);
        *(u16x4*)(reg4 + 640 + c15 * 40 + q) = vv.u;
      }
    }
    // ---- c2e1: c1e1(K=32) -> c2e1(20), write into R2 (c1e0 dead) ----
    FragU bc1f; bc1f.u = *(const u16x8*)(reg4 + 1920 + c15 * 40 + g * 8);
#pragma unroll
    for (int nt = 0; nt < 2; ++nt) {
      f32x4 a = MM(wC2b[nt], bc1f, zf);
      const int q = nt * 16 + g * 4;
      if (q < 20) {
        Pk4 vv;
#pragma unroll
        for (int r = 0; r < 4; ++r) vv.b[r] = (__bf16)fmaxf(a[r], 0.f);
        *(u16x4*)(reg4 + 1280 + c15 * 40 + q) = vv.u;
      }
    }

    // ---- c3: e0 from R1, e1 from R2 ----
    FragU bc2e0; bc2e0.u = *(const u16x8*)(reg4 + 640 + c15 * 40 + g * 8);
    f32x4 cd0 = MM(wC3a, bc2e0, zf);
    FragU bc2e1; bc2e1.u = *(const u16x8*)(reg4 + 1280 + c15 * 40 + g * 8);
    f32x4 cd1 = MM(wC3b, bc2e1, zf);

    // ---- outputs: C-frag lane (g,r) holds row n=g*4+r, col sample=c15 ----
    f32x4 cd;
#pragma unroll
    for (int r = 0; r < 4; ++r) cd[r] = ys ? cd1[r] : cd0[r];

    if (g == 0) {
      f32x2 t2v = {at[0], at[1]};
      *(f32x2*)(outT + (size_t)sg * 2) = t2v;
      f32x2 pa = {ap[0], ap[1]}, pb = {ap[2], ap[3]};
      *(f32x2*)(outP + (size_t)sg * 6) = pa;
      *(f32x2*)(outP + (size_t)sg * 6 + 2) = pb;
      f32x2 ca = {cd[0], cd[1]}, cb = {cd[2], cd[3]};
      *(f32x2*)(outC + (size_t)sg * 6) = ca;
      *(f32x2*)(outC + (size_t)sg * 6 + 2) = cb;
    } else if (g == 1) {
      f32x2 pc = {ap[0], ap[1]};
      *(f32x2*)(outP + (size_t)sg * 6 + 4) = pc;
      f32x2 cc = {cd[0], cd[1]};
      *(f32x2*)(outC + (size_t)sg * 6 + 4) = cc;
    }

    it = nit;
  }
}

extern "C" void kernel_launch(void* const* d_in, const int* in_sizes, int n_in,
                              void* d_out, int out_size, void* d_ws, size_t ws_size,
                              hipStream_t stream) {
  (void)in_sizes; (void)n_in; (void)d_ws; (void)ws_size; (void)out_size;
  const float* gx  = (const float*)d_in[0];
  const int*   gy  = (const int*)d_in[1];
  const float* Wf1 = (const float*)d_in[2];  const float* bf1 = (const float*)d_in[3];
  const float* Wf2 = (const float*)d_in[4];  const float* bf2 = (const float*)d_in[5];
  const float* Wt1 = (const float*)d_in[6];  const float* bt1 = (const float*)d_in[7];
  const float* Wt2 = (const float*)d_in[8];  const float* bt2 = (const float*)d_in[9];
  const float* Wp1 = (const float*)d_in[10]; const float* bp1 = (const float*)d_in[11];
  const float* Wp2 = (const float*)d_in[12]; const float* bp2 = (const float*)d_in[13];
  const float* Wp3 = (const float*)d_in[14]; const float* bp3 = (const float*)d_in[15];
  const float* Wc1 = (const float*)d_in[16]; const float* bc1 = (const float*)d_in[17];
  const float* Wc2 = (const float*)d_in[18]; const float* bc2 = (const float*)d_in[19];
  const float* Wc3 = (const float*)d_in[20]; const float* bc3 = (const float*)d_in[21];
  float* out = (float*)d_out;

  cdann_fwd<<<dim3(GRID), dim3(256), 0, stream>>>(
      gx, gy, Wf1, bf1, Wf2, bf2, Wt1, bt1, Wt2, bt2,
      Wp1, bp1, Wp2, bp2, Wp3, bp3, Wc1, bc1, Wc2, bc2, Wc3, bc3, out);
}

// Round 3
// 55.089 us; speedup vs baseline: 1.8259x; 1.8259x over previous
//
#include <hip/hip_runtime.h>
#include <hip/hip_bf16.h>

typedef __bf16 bf8 __attribute__((ext_vector_type(8)));
typedef __bf16 bf4 __attribute__((ext_vector_type(4)));
typedef unsigned short u16x8 __attribute__((ext_vector_type(8)));
typedef unsigned short u16x4 __attribute__((ext_vector_type(4)));
typedef float f32x4 __attribute__((ext_vector_type(4)));
typedef float f32x2 __attribute__((ext_vector_type(2)));

union FragU { u16x8 u; bf8 b; };
union Pk4 { u16x4 u; bf4 b; };

struct __attribute__((packed, aligned(4))) F4u { float v[4]; };
struct __attribute__((packed, aligned(4))) F2u { float v[2]; };

static __device__ __forceinline__ f32x4 MM(const FragU& a, const FragU& b, f32x4 c) {
  return __builtin_amdgcn_mfma_f32_16x16x32_bf16(a.b, b.b, c, 0, 0, 0);
}

#define NBATCH 524288
#define NTIL (NBATCH / 128)   // 128 samples per block-iteration (2 chains x 64)
#define GRID 512

// per-chain per-wave scratch (ushort units): hbuf [16][72] = 1152, 4 regions [16][40] = 2560
#define PWS 3712
#define RG 1152

__global__ __launch_bounds__(256, 2) void cdann_fwd(
    const float* __restrict__ gx, const int* __restrict__ gy,
    const float* __restrict__ gWf1, const float* __restrict__ gbf1,
    const float* __restrict__ gWf2, const float* __restrict__ gbf2,
    const float* __restrict__ gWt1, const float* __restrict__ gbt1,
    const float* __restrict__ gWt2, const float* __restrict__ gbt2,
    const float* __restrict__ gWp1, const float* __restrict__ gbp1,
    const float* __restrict__ gWp2, const float* __restrict__ gbp2,
    const float* __restrict__ gWp3, const float* __restrict__ gbp3,
    const float* __restrict__ gWc1, const float* __restrict__ gbc1,
    const float* __restrict__ gWc2, const float* __restrict__ gbc2,
    const float* __restrict__ gWc3, const float* __restrict__ gbc3,
    float* __restrict__ gout)
{
  __shared__ __align__(16) unsigned short lds[4 * 2 * PWS];   // 59392 B
  const int tid = (int)threadIdx.x;
  const int lane = tid & 63;
  const int w = tid >> 6;
  const int g = lane >> 4;
  const int c15 = lane & 15;
  unsigned short* hbA = lds + w * (2 * PWS);
  unsigned short* rgA = hbA + RG;
  unsigned short* hbB = hbA + PWS;
  unsigned short* rgB = hbB + RG;

  // ---- const-1/zero slots (offsets 20..31 of each region row); never overwritten ----
  {
    u16x4 one0 = {0x3F80u, 0u, 0u, 0u};
    u16x4 zz = {0u, 0u, 0u, 0u};
    unsigned short* rpA = rgA + g * 640 + c15 * 40;
    *(u16x4*)(rpA + 20) = one0; *(u16x4*)(rpA + 24) = zz; *(u16x4*)(rpA + 28) = zz;
    unsigned short* rpB = rgB + g * 640 + c15 * 40;
    *(u16x4*)(rpB + 20) = one0; *(u16x4*)(rpB + 24) = zz; *(u16x4*)(rpB + 28) = zz;
  }

  // ---- build weight fragments: A-operand = W^T, lane: row n=(l&15), k=(l>>4)*8+j ----
  auto mk = [&](int ks, int nt, auto&& src) {
    FragU f;
    const int kb = ks * 32 + g * 8;
    const int n = nt * 16 + c15;
#pragma unroll
    for (int j = 0; j < 8; ++j) f.b[j] = (__bf16)src(kb + j, n);
    return f;
  };
  auto s_f1 = [&](int k, int n) -> float {
    if (k < 30) return gWf1[k * 64 + n];
    if (k == 30) return gbf1[n];
    return 0.f;
  };
  auto s_f2 = [&](int k, int n) -> float {
    return (n < 42) ? gWf2[k * 42 + n] : 0.f;
  };
  auto s_quad = [&](int k, int n) -> float {         // [t1|p1|c1e0|c1e1], N=80, const1 at k=42
    if (n < 20) { if (k < 42) return gWt1[k * 20 + n]; if (k == 42) return gbt1[n]; return 0.f; }
    if (n < 40) { int m = n - 20; if (k < 42) return gWp1[k * 20 + m]; if (k == 42) return gbp1[m]; return 0.f; }
    if (n < 60) { int m = n - 40; if (k < 42) return gWc1[k * 20 + m]; if (k == 42) return gbc1[m]; return 0.f; }
    int m = n - 60;
    if (k < 42) return gWc1[(42 + k) * 20 + m];
    if (k == 42) return gbc1[20 + m];
    return 0.f;
  };
  auto s_t2 = [&](int k, int n) -> float {
    if (n >= 2) return 0.f;
    if (k < 20) return gWt2[k * 2 + n];
    if (k == 20) return gbt2[n];
    return 0.f;
  };
  auto s_p2 = [&](int k, int n) -> float {
    if (n >= 20) return 0.f;
    if (k < 20) return gWp2[k * 20 + n];
    if (k == 20) return gbp2[n];
    return 0.f;
  };
  auto s_p3 = [&](int k, int n) -> float {
    if (n >= 6) return 0.f;
    if (k < 20) return gWp3[k * 6 + n];
    if (k == 20) return gbp3[n];
    return 0.f;
  };
  auto s_c2 = [&](int e, int k, int n) -> float {
    if (n >= 20) return 0.f;
    if (k < 20) return gWc2[(e * 20 + k) * 20 + n];
    if (k == 20) return gbc2[e * 20 + n];
    return 0.f;
  };
  auto s_c3 = [&](int e, int k, int n) -> float {
    if (n >= 6) return 0.f;
    if (k < 20) return gWc3[(e * 20 + k) * 6 + n];
    if (k == 20) return gbc3[e * 6 + n];
    return 0.f;
  };

  FragU wF1[4], wF2[2][3], wQ[2][5];
  FragU wT2, wP2[2], wP3, wC2a[2], wC2b[2], wC3a, wC3b;
#pragma unroll
  for (int nt = 0; nt < 4; ++nt) wF1[nt] = mk(0, nt, s_f1);
#pragma unroll
  for (int ks = 0; ks < 2; ++ks) {
#pragma unroll
    for (int nt = 0; nt < 3; ++nt) wF2[ks][nt] = mk(ks, nt, s_f2);
#pragma unroll
    for (int nt = 0; nt < 5; ++nt) wQ[ks][nt] = mk(ks, nt, s_quad);
  }
  wT2 = mk(0, 0, s_t2);
#pragma unroll
  for (int nt = 0; nt < 2; ++nt) {
    wP2[nt]  = mk(0, nt, s_p2);
    wC2a[nt] = mk(0, nt, [&](int k, int n){ return s_c2(0, k, n); });
    wC2b[nt] = mk(0, nt, [&](int k, int n){ return s_c2(1, k, n); });
  }
  wP3  = mk(0, 0, s_p3);
  wC3a = mk(0, 0, [&](int k, int n){ return s_c3(0, k, n); });
  wC3b = mk(0, 0, [&](int k, int n){ return s_c3(1, k, n); });

  // f2 bias (K=64 full, can't fold)
  f32x4 bF2[3];
#pragma unroll
  for (int nt = 0; nt < 3; ++nt)
#pragma unroll
    for (int r = 0; r < 4; ++r) {
      int n = nt * 16 + g * 4 + r;
      bF2[nt][r] = (n < 42) ? gbf2[n] : 0.f;
    }

  // ---- PIN: make all loop-invariant fragments opaque so they stay in VGPRs ----
#pragma unroll
  for (int nt = 0; nt < 4; ++nt) asm volatile("" : "+v"(wF1[nt].u));
#pragma unroll
  for (int ks = 0; ks < 2; ++ks) {
#pragma unroll
    for (int nt = 0; nt < 3; ++nt) asm volatile("" : "+v"(wF2[ks][nt].u));
#pragma unroll
    for (int nt = 0; nt < 5; ++nt) asm volatile("" : "+v"(wQ[ks][nt].u));
  }
  asm volatile("" : "+v"(wT2.u));
#pragma unroll
  for (int nt = 0; nt < 2; ++nt) {
    asm volatile("" : "+v"(wP2[nt].u));
    asm volatile("" : "+v"(wC2a[nt].u));
    asm volatile("" : "+v"(wC2b[nt].u));
  }
  asm volatile("" : "+v"(wP3.u));
  asm volatile("" : "+v"(wC3a.u));
  asm volatile("" : "+v"(wC3b.u));
#pragma unroll
  for (int nt = 0; nt < 3; ++nt) asm volatile("" : "+v"(bF2[nt]));

  const f32x4 zf = {0.f, 0.f, 0.f, 0.f};
  float* const outT = gout;
  float* const outP = gout + (size_t)2 * NBATCH;
  float* const outC = gout + (size_t)8 * NBATCH;

  // ---- stages ----
  auto st_f1 = [&](FragU& bx, unsigned short* hb) {
    f32x4 aH[4];
#pragma unroll
    for (int nt = 0; nt < 4; ++nt) aH[nt] = MM(wF1[nt], bx, zf);
#pragma unroll
    for (int nt = 0; nt < 4; ++nt) {
      Pk4 hv;
#pragma unroll
      for (int r = 0; r < 4; ++r) hv.b[r] = (__bf16)fmaxf(aH[nt][r], 0.f);
      *(u16x4*)(hb + c15 * 72 + nt * 16 + g * 4) = hv.u;
    }
  };
  auto st_f2 = [&](unsigned short* hb) {
    FragU bh0, bh1;
    bh0.u = *(const u16x8*)(hb + c15 * 72 + g * 8);
    bh1.u = *(const u16x8*)(hb + c15 * 72 + 32 + g * 8);
#pragma unroll
    for (int nt = 0; nt < 3; ++nt) {
      f32x4 a = MM(wF2[1][nt], bh1, MM(wF2[0][nt], bh0, zf));
      float v[4];
#pragma unroll
      for (int r = 0; r < 4; ++r) v[r] = fmaxf(a[r] + bF2[nt][r], 0.f);
      if (nt == 2) {
        if (g == 2) { v[2] = 1.0f; v[3] = 0.f; }
        if (g == 3) { v[0] = 0.f; v[1] = 0.f; v[2] = 0.f; v[3] = 0.f; }
      }
      Pk4 fv;
#pragma unroll
      for (int r = 0; r < 4; ++r) fv.b[r] = (__bf16)v[r];
      *(u16x4*)(hb + c15 * 72 + nt * 16 + g * 4) = fv.u;
    }
    u16x4 zz = {0u, 0u, 0u, 0u};
    *(u16x4*)(hb + c15 * 72 + 48 + g * 4) = zz;
  };
  auto st_quad = [&](unsigned short* hb, unsigned short* rg) {
    FragU be0, be1;
    be0.u = *(const u16x8*)(hb + c15 * 72 + g * 8);
    be1.u = *(const u16x8*)(hb + c15 * 72 + 32 + g * 8);
#pragma unroll
    for (int nt = 0; nt < 5; ++nt) {
      f32x4 a = MM(wQ[1][nt], be1, MM(wQ[0][nt], be0, zf));
      Pk4 vv;
#pragma unroll
      for (int r = 0; r < 4; ++r) vv.b[r] = (__bf16)fmaxf(a[r], 0.f);
      const int q = nt * 16 + g * 4;
      const int reg = q / 20;
      const int off = q - reg * 20;
      *(u16x4*)(rg + reg * 640 + c15 * 40 + off) = vv.u;
    }
  };
  auto st_h1 = [&](f32x4& at, unsigned short* rg) {
    FragU bt; bt.u = *(const u16x8*)(rg + c15 * 40 + g * 8);
    at = MM(wT2, bt, zf);
    FragU bp1f; bp1f.u = *(const u16x8*)(rg + 640 + c15 * 40 + g * 8);
#pragma unroll
    for (int nt = 0; nt < 2; ++nt) {
      f32x4 a = MM(wP2[nt], bp1f, zf);
      const int q = nt * 16 + g * 4;
      if (q < 20) {
        Pk4 vv;
#pragma unroll
        for (int r = 0; r < 4; ++r) vv.b[r] = (__bf16)fmaxf(a[r], 0.f);
        *(u16x4*)(rg + c15 * 40 + q) = vv.u;
      }
    }
  };
  auto st_h2 = [&](unsigned short* rg) {
    FragU bc0; bc0.u = *(const u16x8*)(rg + 1280 + c15 * 40 + g * 8);
#pragma unroll
    for (int nt = 0; nt < 2; ++nt) {
      f32x4 a = MM(wC2a[nt], bc0, zf);
      const int q = nt * 16 + g * 4;
      if (q < 20) {
        Pk4 vv;
#pragma unroll
        for (int r = 0; r < 4; ++r) vv.b[r] = (__bf16)fmaxf(a[r], 0.f);
        *(u16x4*)(rg + 640 + c15 * 40 + q) = vv.u;
      }
    }
    FragU bc1f; bc1f.u = *(const u16x8*)(rg + 1920 + c15 * 40 + g * 8);
#pragma unroll
    for (int nt = 0; nt < 2; ++nt) {
      f32x4 a = MM(wC2b[nt], bc1f, zf);
      const int q = nt * 16 + g * 4;
      if (q < 20) {
        Pk4 vv;
#pragma unroll
        for (int r = 0; r < 4; ++r) vv.b[r] = (__bf16)fmaxf(a[r], 0.f);
        *(u16x4*)(rg + 1280 + c15 * 40 + q) = vv.u;
      }
    }
  };
  auto st_fin = [&](f32x4& ap, f32x4& cd0, f32x4& cd1, unsigned short* rg) {
    FragU bp2f; bp2f.u = *(const u16x8*)(rg + c15 * 40 + g * 8);
    ap = MM(wP3, bp2f, zf);
    FragU bc2e0; bc2e0.u = *(const u16x8*)(rg + 640 + c15 * 40 + g * 8);
    cd0 = MM(wC3a, bc2e0, zf);
    FragU bc2e1; bc2e1.u = *(const u16x8*)(rg + 1280 + c15 * 40 + g * 8);
    cd1 = MM(wC3b, bc2e1, zf);
  };
  auto st_store = [&](const f32x4& at, const f32x4& ap, const f32x4& cd0, const f32x4& cd1,
                      int sg, int ys) {
    f32x4 cd;
#pragma unroll
    for (int r = 0; r < 4; ++r) cd[r] = ys ? cd1[r] : cd0[r];
    if (g == 0) {
      f32x2 t2v = {at[0], at[1]};
      *(f32x2*)(outT + (size_t)sg * 2) = t2v;
      f32x2 pa = {ap[0], ap[1]}, pb = {ap[2], ap[3]};
      *(f32x2*)(outP + (size_t)sg * 6) = pa;
      *(f32x2*)(outP + (size_t)sg * 6 + 2) = pb;
      f32x2 ca = {cd[0], cd[1]}, cb = {cd[2], cd[3]};
      *(f32x2*)(outC + (size_t)sg * 6) = ca;
      *(f32x2*)(outC + (size_t)sg * 6 + 2) = cb;
    } else if (g == 1) {
      f32x2 pc = {ap[0], ap[1]};
      *(f32x2*)(outP + (size_t)sg * 6 + 4) = pc;
      f32x2 cc = {cd[0], cd[1]};
      *(f32x2*)(outC + (size_t)sg * 6 + 4) = cc;
    }
  };

  // ---- x/y prefetch: lane (g,c15) reads x[s][g*8 .. g*8+7] for chains A (+0) and B (+64) ----
  float xrA[8], xrB[8];
  int yA, yB;
  auto loadx = [&](int it) {
    const int sA = it * 128 + w * 16 + c15;
    const float* xpA = gx + (size_t)sA * 30 + g * 8;
    const float* xpB = xpA + (size_t)64 * 30;
    if (g < 3) {
      F4u a0 = *(const F4u*)xpA; F4u a1 = *(const F4u*)(xpA + 4);
      F4u b0 = *(const F4u*)xpB; F4u b1 = *(const F4u*)(xpB + 4);
#pragma unroll
      for (int j = 0; j < 4; ++j) {
        xrA[j] = a0.v[j]; xrA[4 + j] = a1.v[j];
        xrB[j] = b0.v[j]; xrB[4 + j] = b1.v[j];
      }
    } else {
      F4u a0 = *(const F4u*)xpA; F2u a1 = *(const F2u*)(xpA + 4);
      F4u b0 = *(const F4u*)xpB; F2u b1 = *(const F2u*)(xpB + 4);
#pragma unroll
      for (int j = 0; j < 4; ++j) { xrA[j] = a0.v[j]; xrB[j] = b0.v[j]; }
      xrA[4] = a1.v[0]; xrA[5] = a1.v[1]; xrA[6] = 1.0f; xrA[7] = 0.0f;
      xrB[4] = b1.v[0]; xrB[5] = b1.v[1]; xrB[6] = 1.0f; xrB[7] = 0.0f;
    }
    yA = gy[sA]; yB = gy[sA + 64];
  };

  int it = (int)blockIdx.x;
  loadx(it);

  while (it < NTIL) {
    const int nit = it + GRID;
    const int sgA = it * 128 + w * 16 + c15;
    const int sgB = sgA + 64;
    const int ysA = yA, ysB = yB;

    FragU bxA, bxB;
#pragma unroll
    for (int j = 0; j < 8; ++j) { bxA.b[j] = (__bf16)xrA[j]; bxB.b[j] = (__bf16)xrB[j]; }

    if (nit < NTIL) loadx(nit);   // next tile's loads fly under the chains

    st_f1(bxA, hbA);  st_f1(bxB, hbB);
    st_f2(hbA);       st_f2(hbB);
    st_quad(hbA, rgA); st_quad(hbB, rgB);
    f32x4 atA, atB;
    st_h1(atA, rgA);  st_h1(atB, rgB);
    st_h2(rgA);       st_h2(rgB);
    f32x4 apA, cd0A, cd1A, apB, cd0B, cd1B;
    st_fin(apA, cd0A, cd1A, rgA); st_fin(apB, cd0B, cd1B, rgB);

    st_store(atA, apA, cd0A, cd1A, sgA, ysA);
    st_store(atB, apB, cd0B, cd1B, sgB, ysB);

    it = nit;
  }
}

extern "C" void kernel_launch(void* const* d_in, const int* in_sizes, int n_in,
                              void* d_out, int out_size, void* d_ws, size_t ws_size,
                              hipStream_t stream) {
  (void)in_sizes; (void)n_in; (void)d_ws; (void)ws_size; (void)out_size;
  const float* gx  = (const float*)d_in[0];
  const int*   gy  = (const int*)d_in[1];
  const float* Wf1 = (const float*)d_in[2];  const float* bf1 = (const float*)d_in[3];
  const float* Wf2 = (const float*)d_in[4];  const float* bf2 = (const float*)d_in[5];
  const float* Wt1 = (const float*)d_in[6];  const float* bt1 = (const float*)d_in[7];
  const float* Wt2 = (const float*)d_in[8];  const float* bt2 = (const float*)d_in[9];
  const float* Wp1 = (const float*)d_in[10]; const float* bp1 = (const float*)d_in[11];
  const float* Wp2 = (const float*)d_in[12]; const float* bp2 = (const float*)d_in[13];
  const float* Wp3 = (const float*)d_in[14]; const float* bp3 = (const float*)d_in[15];
  const float* Wc1 = (const float*)d_in[16]; const float* bc1 = (const float*)d_in[17];
  const float* Wc2 = (const float*)d_in[18]; const float* bc2 = (const float*)d_in[19];
  const float* Wc3 = (const float*)d_in[20]; const float* bc3 = (const float*)d_in[21];
  float* out = (float*)d_out;

  cdann_fwd<<<dim3(GRID), dim3(256), 0, stream>>>(
      gx, gy, Wf1, bf1, Wf2, bf2, Wt1, bt1, Wt2, bt2,
      Wp1, bp1, Wp2, bp2, Wp3, bp3, Wc1, bc1, Wc2, bc2, Wc3, bc3, out);
}

// Round 4
// 45.129 us; speedup vs baseline: 2.2288x; 1.2207x over previous
//
#include <hip/hip_runtime.h>
#include <hip/hip_bf16.h>

typedef __bf16 bf8 __attribute__((ext_vector_type(8)));
typedef unsigned short u16x8 __attribute__((ext_vector_type(8)));
typedef float f32x4 __attribute__((ext_vector_type(4)));
typedef float f32x2 __attribute__((ext_vector_type(2)));

union FragU { u16x8 u; bf8 b; };

struct __attribute__((packed, aligned(4))) F4u { float v[4]; };
struct __attribute__((packed, aligned(4))) F2u { float v[2]; };

static __device__ __forceinline__ f32x4 MM(const FragU& a, const FragU& b, f32x4 c) {
  return __builtin_amdgcn_mfma_f32_16x16x32_bf16(a.b, b.b, c, 0, 0, 0);
}

#define NBATCH 524288
#define NTIL (NBATCH / 128)   // 128 samples per block-iteration (2 chains x 64)
#define GRID 512

__global__ __launch_bounds__(256, 2) void cdann_fwd(
    const float* __restrict__ gx, const int* __restrict__ gy,
    const float* __restrict__ gWf1, const float* __restrict__ gbf1,
    const float* __restrict__ gWf2, const float* __restrict__ gbf2,
    const float* __restrict__ gWt1, const float* __restrict__ gbt1,
    const float* __restrict__ gWt2, const float* __restrict__ gbt2,
    const float* __restrict__ gWp1, const float* __restrict__ gbp1,
    const float* __restrict__ gWp2, const float* __restrict__ gbp2,
    const float* __restrict__ gWp3, const float* __restrict__ gbp3,
    const float* __restrict__ gWc1, const float* __restrict__ gbc1,
    const float* __restrict__ gWc2, const float* __restrict__ gbc2,
    const float* __restrict__ gWc3, const float* __restrict__ gbc3,
    float* __restrict__ gout)
{
  const int tid = (int)threadIdx.x;
  const int lane = tid & 63;
  const int w = tid >> 6;
  const int g = lane >> 4;
  const int c15 = lane & 15;

  // Generic A-fragment builder: element j holds val(k = ks*32 + g*8 + j, row m = c15, nt)
  auto mkA = [&](int ks, int nt, auto&& val) {
    FragU f;
#pragma unroll
    for (int j = 0; j < 8; ++j) {
      const int k = ks * 32 + g * 8 + j;
      f.b[j] = (__bf16)val(k, (int)c15, nt);
    }
    return f;
  };

  // ---- Stage 1 (f1): out h, permuted so C lands in B-layout.
  // tile nt, row m -> h-feature 32*(nt>>1) + 8*(m>>2) + 4*(nt&1) + (m&3)
  auto v_f1 = [&](int k, int m, int nt) -> float {
    const int n = 32 * (nt >> 1) + 8 * (m >> 2) + 4 * (nt & 1) + (m & 3);
    if (k < 30) return gWf1[k * 64 + n];
    if (k == 30) return gbf1[n];
    return 0.f;
  };

  // ---- Stage 2 (f2): in h natural; out fea in virtual v-space.
  // tiles 0,1: v = 8*(m>>2)+4*nt+(m&3) (= fea feature); tile 2: see colF2.
  auto colF2 = [](int nt, int m) -> int {
    if (nt < 2) return 8 * (m >> 2) + 4 * nt + (m & 3);
    const int gm = m >> 2, r = m & 3;
    if (gm == 0) return 32 + r;
    if (gm == 1) return 36 + r;
    if (gm == 2 && r < 2) return 40 + r;
    return -1;
  };
  auto v_f2 = [&](int k, int m, int nt) -> float {
    const int col = colF2(nt, m);
    return (col >= 0) ? gWf2[k * 42 + col] : 0.f;
  };

  // fea v-slot -> actual fea feature (-2 = bias/const1 row, -1 = zero)
  auto ffea = [](int v) -> int {
    if (v < 36) return v;
    if (v == 36) return -2;
    if (v >= 40 && v <= 43) return v - 4;
    if (v == 48 || v == 49) return v - 8;
    return -1;
  };

  // ---- Stage 3 (quad heads t|p1|c1e0|c1e1): 5 tiles, per-lane slot u = 4*nt+r:
  // u<5 -> (t, 5g+u); 5..9 -> (p1,...); 10..14 -> (c1e0,...); 15..19 -> (c1e1,...)
  auto v_q = [&](int k, int m, int nt) -> float {
    const int i = ffea(k);
    if (i == -1) return 0.f;
    const int gm = m >> 2;
    const int u = 4 * nt + (m & 3);
    const int head = u / 5;
    const int f = 5 * gm + (u % 5);
    if (head == 0) return (i == -2) ? gbt1[f] : gWt1[i * 20 + f];
    if (head == 1) return (i == -2) ? gbp1[f] : gWp1[i * 20 + f];
    if (head == 2) return (i == -2) ? gbc1[f] : gWc1[i * 20 + f];
    return (i == -2) ? gbc1[20 + f] : gWc1[(42 + i) * 20 + f];
  };

  // ---- Stage 4a ([t;p1] -> [t2|p2]): B v3-space: q0: j<5 t-feat 5gk+j, j==7,gk==0 const1;
  // q1: j<5 p1-feat 5gk+j. Cols: u<5 -> p2 col 5gm+u; u==5,g0 -> t2[0]; u==6,g0 -> t2[1].
  auto v_tp = [&](int k, int m, int nt) -> float {
    const int ks = k >> 5, j = k & 7, gk = (k >> 3) & 3;
    const int gm = m >> 2;
    const int u = 4 * nt + (m & 3);
    const int isP2 = (u < 5);
    const int cp = 5 * gm + u;                 // p2 col if isP2
    const int isT2 = (!isP2 && gm == 0 && (u == 5 || u == 6));
    const int ct = u - 5;                      // t2 col if isT2
    if (ks == 0) {
      if (j < 5) { const int i = 5 * gk + j; return isT2 ? gWt2[i * 2 + ct] : 0.f; }
      if (j == 7 && gk == 0) { if (isT2) return gbt2[ct]; if (isP2) return gbp2[cp]; }
      return 0.f;
    } else {
      if (j < 5) { const int i = 5 * gk + j; return isP2 ? gWp2[i * 20 + cp] : 0.f; }
      return 0.f;
    }
  };

  // ---- Stage 4b ([c1e0;c1e1] -> [c2e0|c2e1]): cols: u<5 -> c2e0 5gm+u; 5..9 -> c2e1 5gm+u-5.
  auto v_cc = [&](int k, int m, int nt) -> float {
    const int ks = k >> 5, j = k & 7, gk = (k >> 3) & 3;
    const int gm = m >> 2;
    const int u = 4 * nt + (m & 3);
    const int isE0 = (u < 5);
    const int isE1 = (u >= 5 && u < 10);
    const int c0 = 5 * gm + u;
    const int c1 = 5 * gm + (u - 5);
    if (ks == 0) {
      if (j < 5) { const int i = 5 * gk + j; return isE0 ? gWc2[i * 20 + c0] : 0.f; }
      if (j == 7 && gk == 0) { if (isE0) return gbc2[c0]; if (isE1) return gbc2[20 + c1]; }
      return 0.f;
    } else {
      if (j < 5) { const int i = 5 * gk + j; return isE1 ? gWc2[(20 + i) * 20 + c1] : 0.f; }
      return 0.f;
    }
  };

  // ---- Stage 5 ([p2;c2e0;c2e1] -> [pd|cd0|cd1]): B v5-space:
  // q0: j<5 p2 5gk+j; j=5,6 c2e1 5gk+(j-5); j==7,gk0 const1.
  // q1: j<5 c2e0 5gk+j; j=5..7 c2e1 5gk+2+(j-5).
  // Cols: nt0: g0 pd r; g1 r<2 pd 4+r else cd0 r-2; g2 cd0 2+r; g3 cd1 r. nt1: g0 r<2 cd1 4+r.
  auto v_o = [&](int k, int m, int nt) -> float {
    const int ks = k >> 5, j = k & 7, gk = (k >> 3) & 3;
    const int gm = m >> 2, r = m & 3;
    int kind = -1, c = 0;   // kind: 0=pd, 1=cd0, 2=cd1
    if (nt == 0) {
      if (gm == 0) { kind = 0; c = r; }
      else if (gm == 1) { if (r < 2) { kind = 0; c = 4 + r; } else { kind = 1; c = r - 2; } }
      else if (gm == 2) { kind = 1; c = 2 + r; }
      else { kind = 2; c = r; }
    } else {
      if (gm == 0 && r < 2) { kind = 2; c = 4 + r; }
    }
    if (kind < 0) return 0.f;
    if (ks == 0) {
      if (j < 5) { const int i = 5 * gk + j; return (kind == 0) ? gWp3[i * 6 + c] : 0.f; }
      if (j < 7) { const int i = 5 * gk + (j - 5); return (kind == 2) ? gWc3[(20 + i) * 6 + c] : 0.f; }
      if (gk == 0) { // bias row
        if (kind == 0) return gbp3[c];
        if (kind == 1) return gbc3[c];
        return gbc3[6 + c];
      }
      return 0.f;
    } else {
      if (j < 5) { const int i = 5 * gk + j; return (kind == 1) ? gWc3[i * 6 + c] : 0.f; }
      const int i = 5 * gk + 2 + (j - 5);
      return (kind == 2) ? gWc3[(20 + i) * 6 + c] : 0.f;
    }
  };

  // ---- build all fragments ----
  FragU wF1[4], wF2[2][3], wQ[2][5], wTP[2][2], wCC[2][3], wO[2][2];
#pragma unroll
  for (int nt = 0; nt < 4; ++nt) wF1[nt] = mkA(0, nt, v_f1);
#pragma unroll
  for (int ks = 0; ks < 2; ++ks) {
#pragma unroll
    for (int nt = 0; nt < 3; ++nt) wF2[ks][nt] = mkA(ks, nt, v_f2);
#pragma unroll
    for (int nt = 0; nt < 5; ++nt) wQ[ks][nt] = mkA(ks, nt, v_q);
#pragma unroll
    for (int nt = 0; nt < 2; ++nt) wTP[ks][nt] = mkA(ks, nt, v_tp);
#pragma unroll
    for (int nt = 0; nt < 3; ++nt) wCC[ks][nt] = mkA(ks, nt, v_cc);
#pragma unroll
    for (int nt = 0; nt < 2; ++nt) wO[ks][nt] = mkA(ks, nt, v_o);
  }

  // f2 bias (f32, per-lane for its own output cols)
  f32x4 bF2[3];
#pragma unroll
  for (int nt = 0; nt < 3; ++nt)
#pragma unroll
    for (int r = 0; r < 4; ++r) {
      const int col = colF2(nt, g * 4 + r);
      bF2[nt][r] = (col >= 0) ? gbf2[col] : 0.f;
    }

  // ---- pin loop-invariants in registers (anti-remat) ----
#pragma unroll
  for (int nt = 0; nt < 4; ++nt) asm volatile("" : "+v"(wF1[nt].u));
#pragma unroll
  for (int ks = 0; ks < 2; ++ks) {
#pragma unroll
    for (int nt = 0; nt < 3; ++nt) asm volatile("" : "+v"(wF2[ks][nt].u));
#pragma unroll
    for (int nt = 0; nt < 5; ++nt) asm volatile("" : "+v"(wQ[ks][nt].u));
#pragma unroll
    for (int nt = 0; nt < 2; ++nt) asm volatile("" : "+v"(wTP[ks][nt].u));
#pragma unroll
    for (int nt = 0; nt < 3; ++nt) asm volatile("" : "+v"(wCC[ks][nt].u));
#pragma unroll
    for (int nt = 0; nt < 2; ++nt) asm volatile("" : "+v"(wO[ks][nt].u));
  }
#pragma unroll
  for (int nt = 0; nt < 3; ++nt) asm volatile("" : "+v"(bF2[nt]));

  const f32x4 zf = {0.f, 0.f, 0.f, 0.f};
  const __bf16 one = (__bf16)1.0f;
  const __bf16 zero = (__bf16)0.0f;
  float* const outT = gout;
  float* const outP = gout + (size_t)2 * NBATCH;
  float* const outC = gout + (size_t)8 * NBATCH;

  // ---- per-chain pipeline: everything in registers ----
  auto chain = [&](const FragU& bx, int s, int y) {
    // f1
    f32x4 aH[4];
#pragma unroll
    for (int nt = 0; nt < 4; ++nt) aH[nt] = MM(wF1[nt], bx, zf);
    FragU bh0, bh1;
#pragma unroll
    for (int j = 0; j < 8; ++j) {
      bh0.b[j] = (__bf16)fmaxf(aH[j >> 2][j & 3], 0.f);
      bh1.b[j] = (__bf16)fmaxf(aH[2 + (j >> 2)][j & 3], 0.f);
    }
    // f2
    f32x4 aF[3];
#pragma unroll
    for (int nt = 0; nt < 3; ++nt) aF[nt] = MM(wF2[1][nt], bh1, MM(wF2[0][nt], bh0, zf));
    FragU bf0, bf1;
#pragma unroll
    for (int j = 0; j < 8; ++j)
      bf0.b[j] = (__bf16)fmaxf(aF[j >> 2][j & 3] + bF2[j >> 2][j & 3], 0.f);
#pragma unroll
    for (int j = 0; j < 4; ++j)
      bf1.b[j] = (__bf16)fmaxf(aF[2][j] + bF2[2][j], 0.f);
    bf1.b[4] = (g == 0) ? one : zero;   // v=36: const1 (head-bias row)
    bf1.b[5] = zero; bf1.b[6] = zero; bf1.b[7] = zero;
    // quad heads
    f32x4 aQ[5];
#pragma unroll
    for (int nt = 0; nt < 5; ++nt) aQ[nt] = MM(wQ[1][nt], bf1, MM(wQ[0][nt], bf0, zf));
    auto rq = [&](int u) { return (__bf16)fmaxf(aQ[u >> 2][u & 3], 0.f); };
    FragU tp0, tp1, cc0, cc1;
#pragma unroll
    for (int j = 0; j < 5; ++j) {
      tp0.b[j] = rq(j);
      tp1.b[j] = rq(5 + j);
      cc0.b[j] = rq(10 + j);
      cc1.b[j] = rq(15 + j);
    }
    tp0.b[5] = zero; tp0.b[6] = zero; tp0.b[7] = (g == 0) ? one : zero;
    tp1.b[5] = zero; tp1.b[6] = zero; tp1.b[7] = zero;
    cc0.b[5] = zero; cc0.b[6] = zero; cc0.b[7] = (g == 0) ? one : zero;
    cc1.b[5] = zero; cc1.b[6] = zero; cc1.b[7] = zero;
    // [t2|p2] and [c2e0|c2e1]
    f32x4 aT[2], aC[3];
#pragma unroll
    for (int nt = 0; nt < 2; ++nt) aT[nt] = MM(wTP[1][nt], tp1, MM(wTP[0][nt], tp0, zf));
#pragma unroll
    for (int nt = 0; nt < 3; ++nt) aC[nt] = MM(wCC[1][nt], cc1, MM(wCC[0][nt], cc0, zf));
    // final B-frag [p2;c2e0;c2e1]+const
    FragU f50, f51;
#pragma unroll
    for (int j = 0; j < 4; ++j) {
      f50.b[j] = (__bf16)fmaxf(aT[0][j], 0.f);
      f51.b[j] = (__bf16)fmaxf(aC[0][j], 0.f);
    }
    f50.b[4] = (__bf16)fmaxf(aT[1][0], 0.f);
    f50.b[5] = (__bf16)fmaxf(aC[1][1], 0.f);
    f50.b[6] = (__bf16)fmaxf(aC[1][2], 0.f);
    f50.b[7] = (g == 0) ? one : zero;
    f51.b[4] = (__bf16)fmaxf(aC[1][0], 0.f);
    f51.b[5] = (__bf16)fmaxf(aC[1][3], 0.f);
    f51.b[6] = (__bf16)fmaxf(aC[2][0], 0.f);
    f51.b[7] = (__bf16)fmaxf(aC[2][1], 0.f);
    // [pd|cd0|cd1]
    f32x4 aO[2];
#pragma unroll
    for (int nt = 0; nt < 2; ++nt) aO[nt] = MM(wO[1][nt], f51, MM(wO[0][nt], f50, zf));
    // stores (raw logits)
    if (g == 0) {
      f32x2 t2v = {aT[1][1], aT[1][2]};
      *(f32x2*)(outT + (size_t)s * 2) = t2v;
      f32x2 pa = {aO[0][0], aO[0][1]}, pb = {aO[0][2], aO[0][3]};
      *(f32x2*)(outP + (size_t)s * 6) = pa;
      *(f32x2*)(outP + (size_t)s * 6 + 2) = pb;
      if (y) { f32x2 cv = {aO[1][0], aO[1][1]}; *(f32x2*)(outC + (size_t)s * 6 + 4) = cv; }
    } else if (g == 1) {
      f32x2 pc = {aO[0][0], aO[0][1]};
      *(f32x2*)(outP + (size_t)s * 6 + 4) = pc;
      if (!y) { f32x2 cv = {aO[0][2], aO[0][3]}; *(f32x2*)(outC + (size_t)s * 6) = cv; }
    } else if (g == 2) {
      if (!y) {
        f32x2 ca = {aO[0][0], aO[0][1]}, cb = {aO[0][2], aO[0][3]};
        *(f32x2*)(outC + (size_t)s * 6 + 2) = ca;
        *(f32x2*)(outC + (size_t)s * 6 + 4) = cb;
      }
    } else {
      if (y) {
        f32x2 ca = {aO[0][0], aO[0][1]}, cb = {aO[0][2], aO[0][3]};
        *(f32x2*)(outC + (size_t)s * 6) = ca;
        *(f32x2*)(outC + (size_t)s * 6 + 2) = cb;
      }
    }
  };

  // ---- x/y prefetch: lane (g,c15) reads x[s][g*8..g*8+7]; chains A(+0), B(+64) ----
  float xrA[8], xrB[8];
  int yA, yB;
  auto loadx = [&](int it) {
    const int sA = it * 128 + w * 16 + c15;
    const float* xpA = gx + (size_t)sA * 30 + g * 8;
    const float* xpB = xpA + (size_t)64 * 30;
    if (g < 3) {
      F4u a0 = *(const F4u*)xpA; F4u a1 = *(const F4u*)(xpA + 4);
      F4u b0 = *(const F4u*)xpB; F4u b1 = *(const F4u*)(xpB + 4);
#pragma unroll
      for (int j = 0; j < 4; ++j) {
        xrA[j] = a0.v[j]; xrA[4 + j] = a1.v[j];
        xrB[j] = b0.v[j]; xrB[4 + j] = b1.v[j];
      }
    } else {
      F4u a0 = *(const F4u*)xpA; F2u a1 = *(const F2u*)(xpA + 4);
      F4u b0 = *(const F4u*)xpB; F2u b1 = *(const F2u*)(xpB + 4);
#pragma unroll
      for (int j = 0; j < 4; ++j) { xrA[j] = a0.v[j]; xrB[j] = b0.v[j]; }
      xrA[4] = a1.v[0]; xrA[5] = a1.v[1]; xrA[6] = 1.0f; xrA[7] = 0.0f;
      xrB[4] = b1.v[0]; xrB[5] = b1.v[1]; xrB[6] = 1.0f; xrB[7] = 0.0f;
    }
    yA = gy[sA]; yB = gy[sA + 64];
  };

  int it = (int)blockIdx.x;
  loadx(it);

  while (it < NTIL) {
    const int nit = it + GRID;
    const int sgA = it * 128 + w * 16 + c15;
    const int sgB = sgA + 64;
    const int ysA = yA, ysB = yB;

    FragU bxA, bxB;
#pragma unroll
    for (int j = 0; j < 8; ++j) { bxA.b[j] = (__bf16)xrA[j]; bxB.b[j] = (__bf16)xrB[j]; }

    if (nit < NTIL) loadx(nit);   // next tile's loads fly under the chains

    chain(bxA, sgA, ysA);
    chain(bxB, sgB, ysB);

    it = nit;
  }
}

extern "C" void kernel_launch(void* const* d_in, const int* in_sizes, int n_in,
                              void* d_out, int out_size, void* d_ws, size_t ws_size,
                              hipStream_t stream) {
  (void)in_sizes; (void)n_in; (void)d_ws; (void)ws_size; (void)out_size;
  const float* gx  = (const float*)d_in[0];
  const int*   gy  = (const int*)d_in[1];
  const float* Wf1 = (const float*)d_in[2];  const float* bf1 = (const float*)d_in[3];
  const float* Wf2 = (const float*)d_in[4];  const float* bf2 = (const float*)d_in[5];
  const float* Wt1 = (const float*)d_in[6];  const float* bt1 = (const float*)d_in[7];
  const float* Wt2 = (const float*)d_in[8];  const float* bt2 = (const float*)d_in[9];
  const float* Wp1 = (const float*)d_in[10]; const float* bp1 = (const float*)d_in[11];
  const float* Wp2 = (const float*)d_in[12]; const float* bp2 = (const float*)d_in[13];
  const float* Wp3 = (const float*)d_in[14]; const float* bp3 = (const float*)d_in[15];
  const float* Wc1 = (const float*)d_in[16]; const float* bc1 = (const float*)d_in[17];
  const float* Wc2 = (const float*)d_in[18]; const float* bc2 = (const float*)d_in[19];
  const float* Wc3 = (const float*)d_in[20]; const float* bc3 = (const float*)d_in[21];
  float* out = (float*)d_out;

  cdann_fwd<<<dim3(GRID), dim3(256), 0, stream>>>(
      gx, gy, Wf1, bf1, Wf2, bf2, Wt1, bt1, Wt2, bt2,
      Wp1, bp1, Wp2, bp2, Wp3, bp3, Wc1, bc1, Wc2, bc2, Wc3, bc3, out);
}